// Round 5
// baseline (136.185 us; speedup 1.0000x reference)
//
#include <hip/hip_runtime.h>

// DcorLoss: dcor(x, y) for x,y [8192,128] fp32 -> single scalar.
//
// <HaH,HbH> = sum(a_ij b_ij) - (2/n) sum_i ra_i rb_i + Sa Sb/n^2: one fused
// pass over pair-tiles: bf16 gram (MFMA 16x16x32) -> distances -> f32
// block-local scalar products + row/col sums, f64 per-tile spill. Upper
// triangle only; off-diag tiles doubled + transposed col-sums.
//
// R5: 512-thr blocks (8 waves x 64x32 quadrants) cut acc regs 128->32;
// X distances held as packed bf16 (numerically negligible: ~3e-5 on dcor).
// Issue-early/write-late staging overlaps global latency with MFMA.
// All-f32 combine (f64 only per-tile). Target: <=128 VGPR -> 16 waves/CU.

typedef float f32x4 __attribute__((ext_vector_type(4)));
typedef __bf16 bf16x8 __attribute__((ext_vector_type(8)));
typedef __bf16 bf16x2 __attribute__((ext_vector_type(2)));

#define NR 8192
#define D 128
#define TILE 128
#define GB 64          /* NR / TILE */
#define NT 2080        /* GB*(GB+1)/2 */
#define BK 64

// ---------------- workspace layout (bytes) ----------------
#define OFF_YB  2097152u
#define OFF_NX  4194304u
#define OFF_NY  (OFF_NX + 32768u)
#define OFF_RPX (OFF_NY + 32768u)               /* 64*64*128 f32 = 2 MB */
#define OFF_RPY (OFF_RPX + 2097152u)            /* 2 MB */
#define OFF_PP  (OFF_RPY + 2097152u)            /* 3*2080 f64 */
#define OFF_SB  (OFF_PP + 49920u)               /* 64*5 f64 */
#define WS_NEED (OFF_SB + 2560u)

__device__ __forceinline__ unsigned short bf16_rne(float f) {
    union { float f; unsigned u; } c; c.f = f;
    unsigned u = c.u;
    u += 0x7FFFu + ((u >> 16) & 1u);
    return (unsigned short)(u >> 16);
}

// One wave per row: fp32 -> bf16 (RNE) + fp32 row sq-norm.
__global__ __launch_bounds__(256) void prep_kernel(
    const float* __restrict__ x, const float* __restrict__ y,
    unsigned short* __restrict__ xb, unsigned short* __restrict__ yb,
    float* __restrict__ nx, float* __restrict__ ny)
{
    int gid = blockIdx.x * 256 + threadIdx.x;
    int wave = gid >> 6;
    int lane = threadIdx.x & 63;
    const float* src; unsigned short* db; float* dn; int row;
    if (wave < NR) { src = x; db = xb; dn = nx; row = wave; }
    else           { src = y; db = yb; dn = ny; row = wave - NR; }

    const float2 v = *reinterpret_cast<const float2*>(src + (size_t)row * D + lane * 2);
    float s = v.x * v.x + v.y * v.y;
    unsigned packed = (unsigned)bf16_rne(v.x) | ((unsigned)bf16_rne(v.y) << 16);
    *reinterpret_cast<unsigned*>(db + (size_t)row * D + lane * 2) = packed;
#pragma unroll
    for (int m = 1; m < 64; m <<= 1) s += __shfl_xor(s, m);
    if (lane == 0) dn[row] = s;
}

// One 128x128 pair-tile per block, 8 waves (2 row x 4 col quadrants of
// 64x32), 4x2 frags of mfma_f32_16x16x32_bf16, K in 2 chunks of 64 with
// register prefetch (issue-early / ds_write-late).
__global__ __launch_bounds__(512, 4) void dcor_main3(
    const unsigned short* __restrict__ xb, const unsigned short* __restrict__ yb,
    const float* __restrict__ nx, const float* __restrict__ ny,
    float* __restrict__ RPx, float* __restrict__ RPy,
    double* __restrict__ Pp /* [3][NT] */)
{
    // triangular index t -> (bi, bj), bi <= bj
    const int t = blockIdx.x;
    double qd = 2.0 * GB + 1.0;
    int bi = (int)((qd - sqrt(qd * qd - 8.0 * (double)t)) * 0.5);
    while (bi > 0 && bi * GB - bi * (bi - 1) / 2 > t) --bi;
    while ((bi + 1) * GB - (bi + 1) * bi / 2 <= t) ++bi;
    const int bj = bi + (t - (bi * GB - bi * (bi - 1) / 2));
    const bool diag = (bi == bj);

    __shared__ __align__(16) unsigned short Ti[TILE][BK + 8]; // 144B stride
    __shared__ __align__(16) unsigned short Tj[TILE][BK + 8];
    __shared__ float nl[2][TILE];        // sq-norms: [0]=rows(bi), [1]=cols(bj)
    __shared__ float rsum[4][TILE];      // x-row, y-row, x-col, y-col
    __shared__ float pr[3][8];           // per-wave scalar partials

    const int tid  = threadIdx.x;
    const int lane = tid & 63, wid = tid >> 6;
    const int wr = wid >> 2, wc = wid & 3;        // 2x4 wave grid
    const int lrow = lane & 15, lkb = lane >> 4;

    if (tid < TILE) {
        nl[0][tid] = nx[bi * TILE + tid];
        nl[1][tid] = nx[bj * TILE + tid];
        rsum[0][tid] = 0.f; rsum[1][tid] = 0.f;
        rsum[2][tid] = 0.f; rsum[3][tid] = 0.f;
    }

    uint4 p[4];
    auto load4 = [&](const unsigned short* srcb, int h) {
        const uint4* s4 = reinterpret_cast<const uint4*>(srcb);
#pragma unroll
        for (int it = 0; it < 4; ++it) {
            int tt = tid + 512 * it;
            int which = tt >> 10, r = (tt >> 3) & (TILE - 1), q = tt & 7;
            int grow = (which ? bj : bi) * TILE + r;
            p[it] = s4[(size_t)grow * 16 + h * 8 + q];
        }
    };
    auto write4 = [&]() {
#pragma unroll
        for (int it = 0; it < 4; ++it) {
            int tt = tid + 512 * it;
            int which = tt >> 10, r = (tt >> 3) & (TILE - 1), q = tt & 7;
            *reinterpret_cast<uint4*>(which ? &Tj[r][q * 8] : &Ti[r][q * 8]) = p[it];
        }
    };

    auto gram_half = [&](f32x4 (&acc)[4][2]) {
#pragma unroll
        for (int kk = 0; kk < 2; ++kk) {
            bf16x8 a[4], b[2];
#pragma unroll
            for (int m = 0; m < 4; ++m)
                a[m] = *reinterpret_cast<const bf16x8*>(
                    &Ti[wr * 64 + m * 16 + lrow][kk * 32 + lkb * 8]);
#pragma unroll
            for (int nf = 0; nf < 2; ++nf)
                b[nf] = *reinterpret_cast<const bf16x8*>(
                    &Tj[wc * 32 + nf * 16 + lrow][kk * 32 + lkb * 8]);
#pragma unroll
            for (int m = 0; m < 4; ++m)
#pragma unroll
                for (int nf = 0; nf < 2; ++nf)
                    acc[m][nf] = __builtin_amdgcn_mfma_f32_16x16x32_bf16(
                        a[m], b[nf], acc[m][nf], 0, 0, 0);
        }
    };

    // C frag: row = (lane>>4)*4 + r, col = lane&15
    auto to_dist = [&](f32x4 (&acc)[4][2]) {
#pragma unroll
        for (int m = 0; m < 4; ++m)
#pragma unroll
            for (int nf = 0; nf < 2; ++nf)
#pragma unroll
                for (int r = 0; r < 4; ++r) {
                    int row_l = wr * 64 + m * 16 + lkb * 4 + r;
                    int col_l = wc * 32 + nf * 16 + lrow;
                    float sq = nl[0][row_l] + nl[1][col_l] - 2.f * acc[m][nf][r];
                    acc[m][nf][r] = sqrtf(fmaxf(sq, 0.f));
                }
        if (diag) {   // wave-uniform: only 64 of 2080 blocks pay this
#pragma unroll
            for (int m = 0; m < 4; ++m)
#pragma unroll
                for (int nf = 0; nf < 2; ++nf)
#pragma unroll
                    for (int r = 0; r < 4; ++r) {
                        int row_l = wr * 64 + m * 16 + lkb * 4 + r;
                        int col_l = wc * 32 + nf * 16 + lrow;
                        if (row_l == col_l) acc[m][nf][r] = 0.f;
                    }
        }
    };

    const f32x4 fz = {0.f, 0.f, 0.f, 0.f};
    f32x4 acc[4][2];
#pragma unroll
    for (int m = 0; m < 4; ++m)
#pragma unroll
        for (int nf = 0; nf < 2; ++nf) acc[m][nf] = fz;

    // ---- pipeline: load early, ds_write late ----
    load4(xb, 0);                                  // X chunk 0 in flight
    write4(); __syncthreads();                     // P1
    load4(xb, 1); gram_half(acc); __syncthreads(); // P2: X1 flies under gram
    write4(); __syncthreads();                     // P3
    load4(yb, 0); gram_half(acc);                  // P4: Y0 flies under gram
    to_dist(acc);
    unsigned dxb[16];                              // X distances -> bf16 pairs
#pragma unroll
    for (int m = 0; m < 4; ++m)
#pragma unroll
        for (int nf = 0; nf < 2; ++nf)
#pragma unroll
            for (int rp = 0; rp < 2; ++rp) {
                bf16x2 pk;
                pk.x = (__bf16)acc[m][nf][2 * rp];
                pk.y = (__bf16)acc[m][nf][2 * rp + 1];
                dxb[m * 4 + nf * 2 + rp] = __builtin_bit_cast(unsigned, pk);
            }
    __syncthreads();
    write4();                                      // P5
    if (tid < TILE) {                              // swap norms to Y
        nl[0][tid] = ny[bi * TILE + tid];
        nl[1][tid] = ny[bj * TILE + tid];
    }
    __syncthreads();
#pragma unroll
    for (int m = 0; m < 4; ++m)
#pragma unroll
        for (int nf = 0; nf < 2; ++nf) acc[m][nf] = fz;
    load4(yb, 1); gram_half(acc); __syncthreads(); // P6
    write4(); __syncthreads();                     // P7
    gram_half(acc);                                // P8
    to_dist(acc);                                  // acc now = Y distances

    // ---- combine: all-f32 block-local ----
    float pxy = 0.f, pxx = 0.f, pyy = 0.f;
    float csx[2] = {0.f, 0.f}, csy[2] = {0.f, 0.f};
#pragma unroll
    for (int m = 0; m < 4; ++m) {
        float rx4[4] = {0.f, 0.f, 0.f, 0.f}, ry4[4] = {0.f, 0.f, 0.f, 0.f};
#pragma unroll
        for (int nf = 0; nf < 2; ++nf)
#pragma unroll
            for (int rp = 0; rp < 2; ++rp) {
                unsigned u = dxb[m * 4 + nf * 2 + rp];
                float dx0 = __builtin_bit_cast(float, u << 16);
                float dx1 = __builtin_bit_cast(float, u & 0xFFFF0000u);
                float dy0 = acc[m][nf][2 * rp], dy1 = acc[m][nf][2 * rp + 1];
                pxy += dx0 * dy0 + dx1 * dy1;
                pxx += dx0 * dx0 + dx1 * dx1;
                pyy += dy0 * dy0 + dy1 * dy1;
                rx4[2 * rp] += dx0;     rx4[2 * rp + 1] += dx1;
                ry4[2 * rp] += dy0;     ry4[2 * rp + 1] += dy1;
                csx[nf] += dx0 + dx1;   csy[nf] += dy0 + dy1;
            }
        // reduce row partials over the 16-lane lrow group
#pragma unroll
        for (int r = 0; r < 4; ++r) {
            float vx = rx4[r], vy = ry4[r];
            vx += __shfl_xor(vx, 1); vx += __shfl_xor(vx, 2);
            vx += __shfl_xor(vx, 4); vx += __shfl_xor(vx, 8);
            vy += __shfl_xor(vy, 1); vy += __shfl_xor(vy, 2);
            vy += __shfl_xor(vy, 4); vy += __shfl_xor(vy, 8);
            if (lrow == 0) {
                int row_l = wr * 64 + m * 16 + lkb * 4 + r;
                atomicAdd(&rsum[0][row_l], vx);
                atomicAdd(&rsum[1][row_l], vy);
            }
        }
    }
    // col sums: reduce across the 4 lkb groups
#pragma unroll
    for (int nf = 0; nf < 2; ++nf) {
        float vx = csx[nf], vy = csy[nf];
        vx += __shfl_xor(vx, 16); vx += __shfl_xor(vx, 32);
        vy += __shfl_xor(vy, 16); vy += __shfl_xor(vy, 32);
        if (lkb == 0) {
            int col_l = wc * 32 + nf * 16 + lrow;
            atomicAdd(&rsum[2][col_l], vx);
            atomicAdd(&rsum[3][col_l], vy);
        }
    }
    // scalar products: wave reduce -> per-wave slot
#pragma unroll
    for (int m = 1; m < 64; m <<= 1) {
        pxy += __shfl_xor(pxy, m);
        pxx += __shfl_xor(pxx, m);
        pyy += __shfl_xor(pyy, m);
    }
    if (lane == 0) { pr[0][wid] = pxy; pr[1][wid] = pxx; pr[2][wid] = pyy; }
    __syncthreads();

    if (tid == 0) {
        double sxy = 0, sxx = 0, syy = 0;
#pragma unroll
        for (int w = 0; w < 8; ++w) {
            sxy += (double)pr[0][w]; sxx += (double)pr[1][w]; syy += (double)pr[2][w];
        }
        double sc = diag ? 1.0 : 2.0;
        Pp[t] = sxy * sc;
        Pp[NT + t] = sxx * sc;
        Pp[2 * NT + t] = syy * sc;
    }
    if (tid < TILE) {   // each RP slot written by exactly one block
        RPx[((size_t)bi * GB + bj) * TILE + tid] = rsum[0][tid];
        RPy[((size_t)bi * GB + bj) * TILE + tid] = rsum[1][tid];
        if (!diag) {
            RPx[((size_t)bj * GB + bi) * TILE + tid] = rsum[2][tid];
            RPy[((size_t)bj * GB + bi) * TILE + tid] = rsum[3][tid];
        }
    }
}

// Fold per-tile partials into full row sums AND the 5 row-sum scalars.
__global__ __launch_bounds__(128) void row_reduce2(
    const float* __restrict__ RPx, const float* __restrict__ RPy,
    double* __restrict__ SB /* [GB][5] */)
{
    int b = blockIdx.x, t = threadIdx.x;
    double rx = 0.0, ry = 0.0;
    for (int k = 0; k < GB; ++k) {
        rx += (double)RPx[((size_t)b * GB + k) * TILE + t];
        ry += (double)RPy[((size_t)b * GB + k) * TILE + t];
    }
    double s0 = rx, s1 = ry, s2 = rx * ry, s3 = rx * rx, s4 = ry * ry;
#pragma unroll
    for (int m = 1; m < 64; m <<= 1) {
        s0 += __shfl_xor(s0, m); s1 += __shfl_xor(s1, m);
        s2 += __shfl_xor(s2, m); s3 += __shfl_xor(s3, m);
        s4 += __shfl_xor(s4, m);
    }
    __shared__ double sb[5][2];
    int lane = t & 63, w = t >> 6;
    if (lane == 0) { sb[0][w] = s0; sb[1][w] = s1; sb[2][w] = s2; sb[3][w] = s3; sb[4][w] = s4; }
    __syncthreads();
    if (t == 0)
#pragma unroll
        for (int i = 0; i < 5; ++i) SB[b * 5 + i] = sb[i][0] + sb[i][1];
}

__global__ __launch_bounds__(256) void dcor_final3(
    const double* __restrict__ SB, const double* __restrict__ Pp,
    unsigned* __restrict__ out)
{
    double sx = 0, sy = 0, sxy = 0, sxx = 0, syy = 0, pxy = 0, pxx = 0, pyy = 0;
    for (int b = threadIdx.x; b < GB; b += 256) {
        sx += SB[b * 5]; sy += SB[b * 5 + 1]; sxy += SB[b * 5 + 2];
        sxx += SB[b * 5 + 3]; syy += SB[b * 5 + 4];
    }
    for (int b = threadIdx.x; b < NT; b += 256) {
        pxy += Pp[b]; pxx += Pp[NT + b]; pyy += Pp[2 * NT + b];
    }
    __shared__ double red[8][4];
    int lane = threadIdx.x & 63, w = threadIdx.x >> 6;
#pragma unroll
    for (int m = 1; m < 64; m <<= 1) {
        sx += __shfl_xor(sx, m);  sy += __shfl_xor(sy, m);
        sxy += __shfl_xor(sxy, m); sxx += __shfl_xor(sxx, m); syy += __shfl_xor(syy, m);
        pxy += __shfl_xor(pxy, m); pxx += __shfl_xor(pxx, m); pyy += __shfl_xor(pyy, m);
    }
    if (lane == 0) {
        red[0][w] = sx;  red[1][w] = sy;  red[2][w] = sxy; red[3][w] = sxx;
        red[4][w] = syy; red[5][w] = pxy; red[6][w] = pxx; red[7][w] = pyy;
    }
    __syncthreads();
    if (threadIdx.x == 0) {
        sx  = red[0][0] + red[0][1] + red[0][2] + red[0][3];
        sy  = red[1][0] + red[1][1] + red[1][2] + red[1][3];
        sxy = red[2][0] + red[2][1] + red[2][2] + red[2][3];
        sxx = red[3][0] + red[3][1] + red[3][2] + red[3][3];
        syy = red[4][0] + red[4][1] + red[4][2] + red[4][3];
        pxy = red[5][0] + red[5][1] + red[5][2] + red[5][3];
        pxx = red[6][0] + red[6][1] + red[6][2] + red[6][3];
        pyy = red[7][0] + red[7][1] + red[7][2] + red[7][3];
        const double inv = 1.0 / (double)NR;
        double vxy = pxy - 2.0 * inv * sxy + sx * sy * inv * inv;
        double vxx = pxx - 2.0 * inv * sxx + sx * sx * inv * inv;
        double vyy = pyy - 2.0 * inv * syy + sy * sy * inv * inv;
        vxy = fmax(vxy, 0.0);
        vxx = fmax(vxx, 1e-30); vyy = fmax(vyy, 1e-30);
        double dcor = -sqrt(vxy) / sqrt(sqrt(vxx) * sqrt(vyy));
        unsigned short b = bf16_rne((float)dcor);
        out[0] = ((unsigned)b << 16) | (unsigned)b;   // f32-and-bf16 valid
    }
}

extern "C" void kernel_launch(void* const* d_in, const int* in_sizes, int n_in,
                              void* d_out, int out_size, void* d_ws, size_t ws_size,
                              hipStream_t stream)
{
    const float* x = (const float*)d_in[0];
    const float* y = (const float*)d_in[1];
    char* ws = (char*)d_ws;
    unsigned short* xb = (unsigned short*)(ws);
    unsigned short* yb = (unsigned short*)(ws + OFF_YB);
    float* nx = (float*)(ws + OFF_NX);
    float* ny = (float*)(ws + OFF_NY);
    float* RPx = (float*)(ws + OFF_RPX);
    float* RPy = (float*)(ws + OFF_RPY);
    double* Pp = (double*)(ws + OFF_PP);
    double* SB = (double*)(ws + OFF_SB);

    prep_kernel<<<4096, 256, 0, stream>>>(x, y, xb, yb, nx, ny);
    dcor_main3<<<NT, 512, 0, stream>>>(xb, yb, nx, ny, RPx, RPy, Pp);
    row_reduce2<<<GB, 128, 0, stream>>>(RPx, RPy, SB);
    dcor_final3<<<1, 256, 0, stream>>>(SB, Pp, (unsigned*)d_out);
}

// Round 6
// 125.029 us; speedup vs baseline: 1.0892x; 1.0892x over previous
//
#include <hip/hip_runtime.h>

// DcorLoss: dcor(x, y) for x,y [8192,128] fp32 -> single scalar.
//
// <HaH,HbH> = sum(a_ij b_ij) - (2/n) sum_i ra_i rb_i + Sa Sb/n^2: one fused
// pass over 128x128 pair-tiles: bf16 gram (MFMA 16x16x32) -> distances ->
// f32 block-local scalar products + row/col sums, f64 per-tile spill.
// Upper triangle only; off-diag tiles doubled + transposed col-sums.
//
// R6: staging via global_load_lds width=16 (linear LDS [128][64], no pad).
// Bank conflicts avoided by PRE-SWIZZLING the bf16 global layout in prep
// (chunk q -> q^(row&7) within each 128B half-row); gram ds_read applies
// the same XOR (both-sides-or-neither rule). 512-thr blocks, 8 waves x
// 64x32 quadrants (acc=32 regs, X dist packed bf16=16 regs); NO waves/EU
// hint (R5's (512,4) forced 64 VGPR -> 300MB scratch spill traffic).

typedef float f32x4 __attribute__((ext_vector_type(4)));
typedef __bf16 bf16x8 __attribute__((ext_vector_type(8)));
typedef __bf16 bf16x2 __attribute__((ext_vector_type(2)));

#define NR 8192
#define D 128
#define TILE 128
#define GB 64          /* NR / TILE */
#define NT 2080        /* GB*(GB+1)/2 */
#define BK 64

// ---------------- workspace layout (bytes) ----------------
#define OFF_YB  2097152u
#define OFF_NX  4194304u
#define OFF_NY  (OFF_NX + 32768u)
#define OFF_RPX (OFF_NY + 32768u)               /* 64*64*128 f32 = 2 MB */
#define OFF_RPY (OFF_RPX + 2097152u)            /* 2 MB */
#define OFF_PP  (OFF_RPY + 2097152u)            /* 3*2080 f64 */
#define OFF_SB  (OFF_PP + 49920u)               /* 64*5 f64 */
#define WS_NEED (OFF_SB + 2560u)

#define GLOAD_LDS16(g, l)                                                  \
    __builtin_amdgcn_global_load_lds(                                      \
        (const __attribute__((address_space(1))) unsigned*)(g),            \
        (__attribute__((address_space(3))) unsigned*)(l), 16, 0, 0)

__device__ __forceinline__ unsigned short bf16_rne(float f) {
    union { float f; unsigned u; } c; c.f = f;
    unsigned u = c.u;
    u += 0x7FFFu + ((u >> 16) & 1u);
    return (unsigned short)(u >> 16);
}

// One wave per row: fp32 -> bf16 (RNE) + fp32 row sq-norm. Output layout is
// CHUNK-SWIZZLED: within each 128B half-row, 16B chunk q stores logical
// chunk q^(row&7), so a linear global_load_lds produces the swizzled LDS
// image that the gram's XOR'd ds_read expects.
__global__ __launch_bounds__(256) void prep_kernel(
    const float* __restrict__ x, const float* __restrict__ y,
    unsigned short* __restrict__ xb, unsigned short* __restrict__ yb,
    float* __restrict__ nx, float* __restrict__ ny)
{
    int gid = blockIdx.x * 256 + threadIdx.x;
    int wave = gid >> 6;
    int lane = threadIdx.x & 63;
    const float* src; unsigned short* db; float* dn; int row;
    if (wave < NR) { src = x; db = xb; dn = nx; row = wave; }
    else           { src = y; db = yb; dn = ny; row = wave - NR; }

    const float2 v = *reinterpret_cast<const float2*>(src + (size_t)row * D + lane * 2);
    float s = v.x * v.x + v.y * v.y;
    unsigned packed = (unsigned)bf16_rne(v.x) | ((unsigned)bf16_rne(v.y) << 16);
    // logical shorts c=lane*2: half h=lane>>5, chunk q=(lane>>2)&7, off=(lane&3)*2
    int h = lane >> 5, q = (lane >> 2) & 7, o = (lane & 3) * 2;
    int sidx = h * 64 + ((q ^ (row & 7)) << 3) + o;
    *reinterpret_cast<unsigned*>(db + (size_t)row * D + sidx) = packed;
#pragma unroll
    for (int m = 1; m < 64; m <<= 1) s += __shfl_xor(s, m);
    if (lane == 0) dn[row] = s;
}

// One 128x128 pair-tile per block, 8 waves (2 row x 4 col quadrants of
// 64x32), 4x2 frags of mfma_f32_16x16x32_bf16, K in 2 chunks of 64.
__global__ __launch_bounds__(512) void dcor_main4(
    const unsigned short* __restrict__ xb, const unsigned short* __restrict__ yb,
    const float* __restrict__ nx, const float* __restrict__ ny,
    float* __restrict__ RPx, float* __restrict__ RPy,
    double* __restrict__ Pp /* [3][NT] */)
{
    // triangular index t -> (bi, bj), bi <= bj
    const int t = blockIdx.x;
    double qd = 2.0 * GB + 1.0;
    int bi = (int)((qd - sqrt(qd * qd - 8.0 * (double)t)) * 0.5);
    while (bi > 0 && bi * GB - bi * (bi - 1) / 2 > t) --bi;
    while ((bi + 1) * GB - (bi + 1) * bi / 2 <= t) ++bi;
    const int bj = bi + (t - (bi * GB - bi * (bi - 1) / 2));
    const bool diag = (bi == bj);

    // linear tiles: 128B row stride (global_load_lds requires linear dest)
    __shared__ __align__(16) unsigned short Ti[TILE][BK];
    __shared__ __align__(16) unsigned short Tj[TILE][BK];
    __shared__ float nl[4][TILE];   // 0:x rows(bi) 1:x cols(bj) 2:y rows 3:y cols
    __shared__ float rsum[4][TILE]; // x-row, y-row, x-col, y-col
    __shared__ float pr[3][8];

    const int tid  = threadIdx.x;
    const int lane = tid & 63, wid = tid >> 6;
    const int wr = wid >> 2, wc = wid & 3;        // 2x4 wave grid
    const int lrow = lane & 15, lkb = lane >> 4;

    if (tid < TILE) {
        nl[0][tid] = nx[bi * TILE + tid];
        nl[1][tid] = nx[bj * TILE + tid];
        nl[2][tid] = ny[bi * TILE + tid];
        nl[3][tid] = ny[bj * TILE + tid];
        rsum[0][tid] = 0.f; rsum[1][tid] = 0.f;
        rsum[2][tid] = 0.f; rsum[3][tid] = 0.f;
    }

    // stage K-half h: 32 x 1KB segments, 4 per wave, pure LDS-DMA.
    // lane l of a segment covers (row r0+l/8, chunk l&7) = LDS base + l*16.
    auto stage = [&](const unsigned short* srcb, int h) {
        const char* gb = (const char*)srcb;
#pragma unroll
        for (int it = 0; it < 4; ++it) {
            int s = wid * 4 + it;
            int tsel = s >> 4;                       // 0 = Ti, 1 = Tj
            int r0 = (s & 15) * 8;
            unsigned short* ldsb = tsel ? &Tj[r0][0] : &Ti[r0][0];
            int grow = (tsel ? bj : bi) * TILE + r0 + (lane >> 3);
            const char* g = gb + (size_t)grow * 256 + h * 128 + (lane & 7) * 16;
            GLOAD_LDS16(g, ldsb);
        }
    };

    auto gram_half = [&](f32x4 (&acc)[4][2]) {
#pragma unroll
        for (int kk = 0; kk < 2; ++kk) {
            // logical 16B chunk q = kk*4+lkb, stored at q^(lrow&7)
            const int sA = (((kk << 2) | lkb) ^ (lrow & 7)) << 4;
            bf16x8 a[4], b[2];
#pragma unroll
            for (int m = 0; m < 4; ++m) {
                int row = wr * 64 + m * 16 + lrow;
                a[m] = *reinterpret_cast<const bf16x8*>(
                    (const char*)&Ti[0][0] + row * 128 + sA);
            }
#pragma unroll
            for (int nf = 0; nf < 2; ++nf) {
                int row = wc * 32 + nf * 16 + lrow;
                b[nf] = *reinterpret_cast<const bf16x8*>(
                    (const char*)&Tj[0][0] + row * 128 + sA);
            }
#pragma unroll
            for (int m = 0; m < 4; ++m)
#pragma unroll
                for (int nf = 0; nf < 2; ++nf)
                    acc[m][nf] = __builtin_amdgcn_mfma_f32_16x16x32_bf16(
                        a[m], b[nf], acc[m][nf], 0, 0, 0);
        }
    };

    // C frag: row = (lane>>4)*4 + r, col = lane&15
    auto to_dist = [&](f32x4 (&acc)[4][2], const float* nR, const float* nC) {
#pragma unroll
        for (int m = 0; m < 4; ++m)
#pragma unroll
            for (int nf = 0; nf < 2; ++nf)
#pragma unroll
                for (int r = 0; r < 4; ++r) {
                    int row_l = wr * 64 + m * 16 + lkb * 4 + r;
                    int col_l = wc * 32 + nf * 16 + lrow;
                    float sq = nR[row_l] + nC[col_l] - 2.f * acc[m][nf][r];
                    acc[m][nf][r] = sqrtf(fmaxf(sq, 0.f));
                }
        if (diag) {   // only 64/2080 blocks
#pragma unroll
            for (int m = 0; m < 4; ++m)
#pragma unroll
                for (int nf = 0; nf < 2; ++nf)
#pragma unroll
                    for (int r = 0; r < 4; ++r) {
                        int row_l = wr * 64 + m * 16 + lkb * 4 + r;
                        int col_l = wc * 32 + nf * 16 + lrow;
                        if (row_l == col_l) acc[m][nf][r] = 0.f;
                    }
        }
    };

    const f32x4 fz = {0.f, 0.f, 0.f, 0.f};
    f32x4 acc[4][2];
#pragma unroll
    for (int m = 0; m < 4; ++m)
#pragma unroll
        for (int nf = 0; nf < 2; ++nf) acc[m][nf] = fz;

    // ---- X gram ----
    stage(xb, 0); __syncthreads();
    gram_half(acc); __syncthreads();
    stage(xb, 1); __syncthreads();
    gram_half(acc); __syncthreads();
    stage(yb, 0);                      // Y0 DMA flies under to_dist/pack
    to_dist(acc, nl[0], nl[1]);
    unsigned dxb[16];                  // X distances -> packed bf16 pairs
#pragma unroll
    for (int m = 0; m < 4; ++m)
#pragma unroll
        for (int nf = 0; nf < 2; ++nf)
#pragma unroll
            for (int rp = 0; rp < 2; ++rp) {
                bf16x2 pk;
                pk.x = (__bf16)acc[m][nf][2 * rp];
                pk.y = (__bf16)acc[m][nf][2 * rp + 1];
                dxb[m * 4 + nf * 2 + rp] = __builtin_bit_cast(unsigned, pk);
            }
#pragma unroll
    for (int m = 0; m < 4; ++m)
#pragma unroll
        for (int nf = 0; nf < 2; ++nf) acc[m][nf] = fz;
    __syncthreads();
    // ---- Y gram ----
    gram_half(acc); __syncthreads();
    stage(yb, 1); __syncthreads();
    gram_half(acc);
    to_dist(acc, nl[2], nl[3]);        // acc = Y distances

    // ---- combine: all-f32 block-local ----
    float pxy = 0.f, pxx = 0.f, pyy = 0.f;
    float csx[2] = {0.f, 0.f}, csy[2] = {0.f, 0.f};
#pragma unroll
    for (int m = 0; m < 4; ++m) {
        float rx4[4] = {0.f, 0.f, 0.f, 0.f}, ry4[4] = {0.f, 0.f, 0.f, 0.f};
#pragma unroll
        for (int nf = 0; nf < 2; ++nf)
#pragma unroll
            for (int rp = 0; rp < 2; ++rp) {
                unsigned u = dxb[m * 4 + nf * 2 + rp];
                float dx0 = __builtin_bit_cast(float, u << 16);
                float dx1 = __builtin_bit_cast(float, u & 0xFFFF0000u);
                float dy0 = acc[m][nf][2 * rp], dy1 = acc[m][nf][2 * rp + 1];
                pxy += dx0 * dy0 + dx1 * dy1;
                pxx += dx0 * dx0 + dx1 * dx1;
                pyy += dy0 * dy0 + dy1 * dy1;
                rx4[2 * rp] += dx0;     rx4[2 * rp + 1] += dx1;
                ry4[2 * rp] += dy0;     ry4[2 * rp + 1] += dy1;
                csx[nf] += dx0 + dx1;   csy[nf] += dy0 + dy1;
            }
#pragma unroll
        for (int r = 0; r < 4; ++r) {
            float vx = rx4[r], vy = ry4[r];
            vx += __shfl_xor(vx, 1); vx += __shfl_xor(vx, 2);
            vx += __shfl_xor(vx, 4); vx += __shfl_xor(vx, 8);
            vy += __shfl_xor(vy, 1); vy += __shfl_xor(vy, 2);
            vy += __shfl_xor(vy, 4); vy += __shfl_xor(vy, 8);
            if (lrow == 0) {
                int row_l = wr * 64 + m * 16 + lkb * 4 + r;
                atomicAdd(&rsum[0][row_l], vx);
                atomicAdd(&rsum[1][row_l], vy);
            }
        }
    }
#pragma unroll
    for (int nf = 0; nf < 2; ++nf) {
        float vx = csx[nf], vy = csy[nf];
        vx += __shfl_xor(vx, 16); vx += __shfl_xor(vx, 32);
        vy += __shfl_xor(vy, 16); vy += __shfl_xor(vy, 32);
        if (lkb == 0) {
            int col_l = wc * 32 + nf * 16 + lrow;
            atomicAdd(&rsum[2][col_l], vx);
            atomicAdd(&rsum[3][col_l], vy);
        }
    }
#pragma unroll
    for (int m = 1; m < 64; m <<= 1) {
        pxy += __shfl_xor(pxy, m);
        pxx += __shfl_xor(pxx, m);
        pyy += __shfl_xor(pyy, m);
    }
    if (lane == 0) { pr[0][wid] = pxy; pr[1][wid] = pxx; pr[2][wid] = pyy; }
    __syncthreads();

    if (tid == 0) {
        double sxy = 0, sxx = 0, syy = 0;
#pragma unroll
        for (int w = 0; w < 8; ++w) {
            sxy += (double)pr[0][w]; sxx += (double)pr[1][w]; syy += (double)pr[2][w];
        }
        double sc = diag ? 1.0 : 2.0;
        Pp[t] = sxy * sc;
        Pp[NT + t] = sxx * sc;
        Pp[2 * NT + t] = syy * sc;
    }
    if (tid < TILE) {   // each RP slot written by exactly one block
        RPx[((size_t)bi * GB + bj) * TILE + tid] = rsum[0][tid];
        RPy[((size_t)bi * GB + bj) * TILE + tid] = rsum[1][tid];
        if (!diag) {
            RPx[((size_t)bj * GB + bi) * TILE + tid] = rsum[2][tid];
            RPy[((size_t)bj * GB + bi) * TILE + tid] = rsum[3][tid];
        }
    }
}

// Fold per-tile partials into full row sums AND the 5 row-sum scalars.
__global__ __launch_bounds__(128) void row_reduce2(
    const float* __restrict__ RPx, const float* __restrict__ RPy,
    double* __restrict__ SB /* [GB][5] */)
{
    int b = blockIdx.x, t = threadIdx.x;
    double rx = 0.0, ry = 0.0;
    for (int k = 0; k < GB; ++k) {
        rx += (double)RPx[((size_t)b * GB + k) * TILE + t];
        ry += (double)RPy[((size_t)b * GB + k) * TILE + t];
    }
    double s0 = rx, s1 = ry, s2 = rx * ry, s3 = rx * rx, s4 = ry * ry;
#pragma unroll
    for (int m = 1; m < 64; m <<= 1) {
        s0 += __shfl_xor(s0, m); s1 += __shfl_xor(s1, m);
        s2 += __shfl_xor(s2, m); s3 += __shfl_xor(s3, m);
        s4 += __shfl_xor(s4, m);
    }
    __shared__ double sb[5][2];
    int lane = t & 63, w = t >> 6;
    if (lane == 0) { sb[0][w] = s0; sb[1][w] = s1; sb[2][w] = s2; sb[3][w] = s3; sb[4][w] = s4; }
    __syncthreads();
    if (t == 0)
#pragma unroll
        for (int i = 0; i < 5; ++i) SB[b * 5 + i] = sb[i][0] + sb[i][1];
}

__global__ __launch_bounds__(256) void dcor_final3(
    const double* __restrict__ SB, const double* __restrict__ Pp,
    unsigned* __restrict__ out)
{
    double sx = 0, sy = 0, sxy = 0, sxx = 0, syy = 0, pxy = 0, pxx = 0, pyy = 0;
    for (int b = threadIdx.x; b < GB; b += 256) {
        sx += SB[b * 5]; sy += SB[b * 5 + 1]; sxy += SB[b * 5 + 2];
        sxx += SB[b * 5 + 3]; syy += SB[b * 5 + 4];
    }
    for (int b = threadIdx.x; b < NT; b += 256) {
        pxy += Pp[b]; pxx += Pp[NT + b]; pyy += Pp[2 * NT + b];
    }
    __shared__ double red[8][4];
    int lane = threadIdx.x & 63, w = threadIdx.x >> 6;
#pragma unroll
    for (int m = 1; m < 64; m <<= 1) {
        sx += __shfl_xor(sx, m);  sy += __shfl_xor(sy, m);
        sxy += __shfl_xor(sxy, m); sxx += __shfl_xor(sxx, m); syy += __shfl_xor(syy, m);
        pxy += __shfl_xor(pxy, m); pxx += __shfl_xor(pxx, m); pyy += __shfl_xor(pyy, m);
    }
    if (lane == 0) {
        red[0][w] = sx;  red[1][w] = sy;  red[2][w] = sxy; red[3][w] = sxx;
        red[4][w] = syy; red[5][w] = pxy; red[6][w] = pxx; red[7][w] = pyy;
    }
    __syncthreads();
    if (threadIdx.x == 0) {
        sx  = red[0][0] + red[0][1] + red[0][2] + red[0][3];
        sy  = red[1][0] + red[1][1] + red[1][2] + red[1][3];
        sxy = red[2][0] + red[2][1] + red[2][2] + red[2][3];
        sxx = red[3][0] + red[3][1] + red[3][2] + red[3][3];
        syy = red[4][0] + red[4][1] + red[4][2] + red[4][3];
        pxy = red[5][0] + red[5][1] + red[5][2] + red[5][3];
        pxx = red[6][0] + red[6][1] + red[6][2] + red[6][3];
        pyy = red[7][0] + red[7][1] + red[7][2] + red[7][3];
        const double inv = 1.0 / (double)NR;
        double vxy = pxy - 2.0 * inv * sxy + sx * sy * inv * inv;
        double vxx = pxx - 2.0 * inv * sxx + sx * sx * inv * inv;
        double vyy = pyy - 2.0 * inv * syy + sy * sy * inv * inv;
        vxy = fmax(vxy, 0.0);
        vxx = fmax(vxx, 1e-30); vyy = fmax(vyy, 1e-30);
        double dcor = -sqrt(vxy) / sqrt(sqrt(vxx) * sqrt(vyy));
        unsigned short b = bf16_rne((float)dcor);
        out[0] = ((unsigned)b << 16) | (unsigned)b;   // f32-and-bf16 valid
    }
}

extern "C" void kernel_launch(void* const* d_in, const int* in_sizes, int n_in,
                              void* d_out, int out_size, void* d_ws, size_t ws_size,
                              hipStream_t stream)
{
    const float* x = (const float*)d_in[0];
    const float* y = (const float*)d_in[1];
    char* ws = (char*)d_ws;
    unsigned short* xb = (unsigned short*)(ws);
    unsigned short* yb = (unsigned short*)(ws + OFF_YB);
    float* nx = (float*)(ws + OFF_NX);
    float* ny = (float*)(ws + OFF_NY);
    float* RPx = (float*)(ws + OFF_RPX);
    float* RPy = (float*)(ws + OFF_RPY);
    double* Pp = (double*)(ws + OFF_PP);
    double* SB = (double*)(ws + OFF_SB);

    prep_kernel<<<4096, 256, 0, stream>>>(x, y, xb, yb, nx, ny);
    dcor_main4<<<NT, 512, 0, stream>>>(xb, yb, nx, ny, RPx, RPy, Pp);
    row_reduce2<<<GB, 128, 0, stream>>>(RPx, RPy, SB);
    dcor_final3<<<1, 256, 0, stream>>>(SB, Pp, (unsigned*)d_out);
}

// Round 7
// 119.006 us; speedup vs baseline: 1.1444x; 1.0506x over previous
//
#include <hip/hip_runtime.h>

// DcorLoss: dcor(x, y) for x,y [8192,128] fp32 -> single scalar.
//
// <HaH,HbH> = sum(a_ij b_ij) - (2/n) sum_i ra_i rb_i + Sa Sb/n^2: one fused
// pass over 128x128 pair-tiles: bf16 gram (MFMA 16x16x32) -> distances ->
// f32 block-local scalar products + row/col sums, f64 per-tile spill.
// Upper triangle only; off-diag tiles doubled + transposed col-sums.
//
// R7: (1) butterfly multi-value reduction for row sums: 15 shuffles per 16
// values (lane ends owning ONE row's full sum -> uniform single atomic),
// replacing 256 ds-shuffles/thread; (2) double-buffered staging cuts
// barriers 8->5, each DMA drain overlapped with gram compute; (3) XCD-
// chunked tile swizzle (2080 % 8 == 0, bijective) for L2-local panels.
// Staging stays global_load_lds w=16 with pre-swizzled global layout (R6).

typedef float f32x4 __attribute__((ext_vector_type(4)));
typedef __bf16 bf16x8 __attribute__((ext_vector_type(8)));
typedef __bf16 bf16x2 __attribute__((ext_vector_type(2)));

#define NR 8192
#define D 128
#define TILE 128
#define GB 64          /* NR / TILE */
#define NT 2080        /* GB*(GB+1)/2 */
#define BK 64

// ---------------- workspace layout (bytes) ----------------
#define OFF_YB  2097152u
#define OFF_NX  4194304u
#define OFF_NY  (OFF_NX + 32768u)
#define OFF_RPX (OFF_NY + 32768u)               /* 64*64*128 f32 = 2 MB */
#define OFF_RPY (OFF_RPX + 2097152u)            /* 2 MB */
#define OFF_PP  (OFF_RPY + 2097152u)            /* 3*2080 f64 */
#define OFF_SB  (OFF_PP + 49920u)               /* 64*5 f64 */
#define WS_NEED (OFF_SB + 2560u)

#define GLOAD_LDS16(g, l)                                                  \
    __builtin_amdgcn_global_load_lds(                                      \
        (const __attribute__((address_space(1))) unsigned*)(g),            \
        (__attribute__((address_space(3))) unsigned*)(l), 16, 0, 0)

__device__ __forceinline__ unsigned short bf16_rne(float f) {
    union { float f; unsigned u; } c; c.f = f;
    unsigned u = c.u;
    u += 0x7FFFu + ((u >> 16) & 1u);
    return (unsigned short)(u >> 16);
}

// One wave per row: fp32 -> bf16 (RNE) + fp32 row sq-norm. Output layout is
// CHUNK-SWIZZLED: within each 128B half-row, 16B chunk q stores logical
// chunk q^(row&7), so a linear global_load_lds produces the swizzled LDS
// image that the gram's XOR'd ds_read expects.
__global__ __launch_bounds__(256) void prep_kernel(
    const float* __restrict__ x, const float* __restrict__ y,
    unsigned short* __restrict__ xb, unsigned short* __restrict__ yb,
    float* __restrict__ nx, float* __restrict__ ny)
{
    int gid = blockIdx.x * 256 + threadIdx.x;
    int wave = gid >> 6;
    int lane = threadIdx.x & 63;
    const float* src; unsigned short* db; float* dn; int row;
    if (wave < NR) { src = x; db = xb; dn = nx; row = wave; }
    else           { src = y; db = yb; dn = ny; row = wave - NR; }

    const float2 v = *reinterpret_cast<const float2*>(src + (size_t)row * D + lane * 2);
    float s = v.x * v.x + v.y * v.y;
    unsigned packed = (unsigned)bf16_rne(v.x) | ((unsigned)bf16_rne(v.y) << 16);
    int h = lane >> 5, q = (lane >> 2) & 7, o = (lane & 3) * 2;
    int sidx = h * 64 + ((q ^ (row & 7)) << 3) + o;
    *reinterpret_cast<unsigned*>(db + (size_t)row * D + sidx) = packed;
#pragma unroll
    for (int m = 1; m < 64; m <<= 1) s += __shfl_xor(s, m);
    if (lane == 0) dn[row] = s;
}

// butterfly step S for a 16-value array reduced over the 16-lane lrow group
#define BSTEP(arr, S) {                                                    \
    const int b_ = (lrow >> (S)) & 1;                                      \
    _Pragma("unroll")                                                      \
    for (int i_ = 0; i_ < (8 >> (S)); ++i_) {                              \
        float k_ = b_ ? arr[2 * i_ + 1] : arr[2 * i_];                     \
        float s_ = b_ ? arr[2 * i_] : arr[2 * i_ + 1];                     \
        arr[i_] = k_ + __shfl_xor(s_, 1 << (S));                           \
    } }

// One 128x128 pair-tile per block, 8 waves (2 row x 4 col quadrants of
// 64x32), 4x2 frags of mfma_f32_16x16x32_bf16, double-buffered K-halves.
__global__ __launch_bounds__(512) void dcor_main5(
    const unsigned short* __restrict__ xb, const unsigned short* __restrict__ yb,
    const float* __restrict__ nx, const float* __restrict__ ny,
    float* __restrict__ RPx, float* __restrict__ RPy,
    double* __restrict__ Pp /* [3][NT] */)
{
    // XCD-chunked swizzle (8 XCDs, NT % 8 == 0 -> bijective)
    const int t = (blockIdx.x & 7) * (NT / 8) + (blockIdx.x >> 3);
    // triangular index t -> (bi, bj), bi <= bj
    double qd = 2.0 * GB + 1.0;
    int bi = (int)((qd - sqrt(qd * qd - 8.0 * (double)t)) * 0.5);
    while (bi > 0 && bi * GB - bi * (bi - 1) / 2 > t) --bi;
    while ((bi + 1) * GB - (bi + 1) * bi / 2 <= t) ++bi;
    const int bj = bi + (t - (bi * GB - bi * (bi - 1) / 2));
    const bool diag = (bi == bj);

    // two staging buffers: [buf][tsel][row][64 shorts] (linear, DMA dest)
    __shared__ __align__(16) unsigned short Buf[2][2][TILE][BK];
    __shared__ float nl[4][TILE];   // 0:x rows 1:x cols 2:y rows 3:y cols
    __shared__ float rsum[4][TILE]; // x-row, y-row, x-col, y-col
    __shared__ float pr[3][8];

    const int tid  = threadIdx.x;
    const int lane = tid & 63, wid = tid >> 6;
    const int wr = wid >> 2, wc = wid & 3;        // 2x4 wave grid
    const int lrow = lane & 15, lkb = lane >> 4;

    if (tid < TILE) {
        nl[0][tid] = nx[bi * TILE + tid];
        nl[1][tid] = nx[bj * TILE + tid];
        nl[2][tid] = ny[bi * TILE + tid];
        nl[3][tid] = ny[bj * TILE + tid];
        rsum[0][tid] = 0.f; rsum[1][tid] = 0.f;
        rsum[2][tid] = 0.f; rsum[3][tid] = 0.f;
    }

    // stage K-half h into buffer b: 32 x 1KB segments, pure LDS-DMA
    auto stage = [&](int b, const unsigned short* srcb, int h) {
        const char* gb = (const char*)srcb;
#pragma unroll
        for (int it = 0; it < 4; ++it) {
            int s = wid * 4 + it;
            int tsel = s >> 4;
            int r0 = (s & 15) * 8;
            unsigned short* ldsb = &Buf[b][tsel][r0][0];
            int grow = (tsel ? bj : bi) * TILE + r0 + (lane >> 3);
            const char* g = gb + (size_t)grow * 256 + h * 128 + (lane & 7) * 16;
            GLOAD_LDS16(g, ldsb);
        }
    };

    auto gram = [&](int b, f32x4 (&acc)[4][2]) {
        const char* Ti = (const char*)&Buf[b][0][0][0];
        const char* Tj = (const char*)&Buf[b][1][0][0];
#pragma unroll
        for (int kk = 0; kk < 2; ++kk) {
            const int sA = (((kk << 2) | lkb) ^ (lrow & 7)) << 4;
            bf16x8 a[4], bb[2];
#pragma unroll
            for (int m = 0; m < 4; ++m) {
                int row = wr * 64 + m * 16 + lrow;
                a[m] = *reinterpret_cast<const bf16x8*>(Ti + row * 128 + sA);
            }
#pragma unroll
            for (int nf = 0; nf < 2; ++nf) {
                int row = wc * 32 + nf * 16 + lrow;
                bb[nf] = *reinterpret_cast<const bf16x8*>(Tj + row * 128 + sA);
            }
#pragma unroll
            for (int m = 0; m < 4; ++m)
#pragma unroll
                for (int nf = 0; nf < 2; ++nf)
                    acc[m][nf] = __builtin_amdgcn_mfma_f32_16x16x32_bf16(
                        a[m], bb[nf], acc[m][nf], 0, 0, 0);
        }
    };

    // C frag: row = (lane>>4)*4 + r, col = lane&15
    auto to_dist = [&](f32x4 (&acc)[4][2], const float* nRw, const float* nC) {
#pragma unroll
        for (int m = 0; m < 4; ++m)
#pragma unroll
            for (int nf = 0; nf < 2; ++nf)
#pragma unroll
                for (int r = 0; r < 4; ++r) {
                    int row_l = wr * 64 + m * 16 + lkb * 4 + r;
                    int col_l = wc * 32 + nf * 16 + lrow;
                    float sq = nRw[row_l] + nC[col_l] - 2.f * acc[m][nf][r];
                    acc[m][nf][r] = sqrtf(fmaxf(sq, 0.f));
                }
        if (diag) {
#pragma unroll
            for (int m = 0; m < 4; ++m)
#pragma unroll
                for (int nf = 0; nf < 2; ++nf)
#pragma unroll
                    for (int r = 0; r < 4; ++r) {
                        int row_l = wr * 64 + m * 16 + lkb * 4 + r;
                        int col_l = wc * 32 + nf * 16 + lrow;
                        if (row_l == col_l) acc[m][nf][r] = 0.f;
                    }
        }
    };

    const f32x4 fz = {0.f, 0.f, 0.f, 0.f};
    f32x4 acc[4][2];
#pragma unroll
    for (int m = 0; m < 4; ++m)
#pragma unroll
        for (int nf = 0; nf < 2; ++nf) acc[m][nf] = fz;

    // ---- double-buffered pipeline: 5 barriers ----
    stage(0, xb, 0);
    __syncthreads();                 // B1: DMA0 done (+ init visible)
    stage(1, xb, 1);                 // DMA1 flies under gram0
    gram(0, acc);
    __syncthreads();                 // B2: DMA1 done, buf0 free
    stage(0, yb, 0);                 // DMA2 flies under gram1 + to_dist
    gram(1, acc);
    to_dist(acc, nl[0], nl[1]);
    unsigned dxb[16];                // X distances -> packed bf16 pairs
#pragma unroll
    for (int m = 0; m < 4; ++m)
#pragma unroll
        for (int nf = 0; nf < 2; ++nf)
#pragma unroll
            for (int rp = 0; rp < 2; ++rp) {
                bf16x2 pk;
                pk.x = (__bf16)acc[m][nf][2 * rp];
                pk.y = (__bf16)acc[m][nf][2 * rp + 1];
                dxb[m * 4 + nf * 2 + rp] = __builtin_bit_cast(unsigned, pk);
            }
#pragma unroll
    for (int m = 0; m < 4; ++m)
#pragma unroll
        for (int nf = 0; nf < 2; ++nf) acc[m][nf] = fz;
    __syncthreads();                 // B3: DMA2 done, buf1 free
    stage(1, yb, 1);                 // DMA3 flies under gram2
    gram(0, acc);
    __syncthreads();                 // B4: DMA3 done
    gram(1, acc);
    to_dist(acc, nl[2], nl[3]);      // acc = Y distances

    // ---- combine ----
    float pxy = 0.f, pxx = 0.f, pyy = 0.f;
    float ax[16], ay[16];
    float csx[2] = {0.f, 0.f}, csy[2] = {0.f, 0.f};
#pragma unroll
    for (int j = 0; j < 16; ++j) { ax[j] = 0.f; ay[j] = 0.f; }

#pragma unroll
    for (int m = 0; m < 4; ++m)
#pragma unroll
        for (int nf = 0; nf < 2; ++nf)
#pragma unroll
            for (int rp = 0; rp < 2; ++rp) {
                unsigned u = dxb[m * 4 + nf * 2 + rp];
                float dx0 = __builtin_bit_cast(float, u << 16);
                float dx1 = __builtin_bit_cast(float, u & 0xFFFF0000u);
                float dy0 = acc[m][nf][2 * rp], dy1 = acc[m][nf][2 * rp + 1];
                pxy += dx0 * dy0 + dx1 * dy1;
                pxx += dx0 * dx0 + dx1 * dx1;
                pyy += dy0 * dy0 + dy1 * dy1;
                ax[m * 4 + 2 * rp] += dx0; ax[m * 4 + 2 * rp + 1] += dx1;
                ay[m * 4 + 2 * rp] += dy0; ay[m * 4 + 2 * rp + 1] += dy1;
                csx[nf] += dx0 + dx1;      csy[nf] += dy0 + dy1;
            }

    // butterfly: 15 shuffles reduce 16 values over the 16-lane lrow group;
    // lane ends holding the full sum for value j == lrow.
    BSTEP(ax, 0) BSTEP(ay, 0)
    BSTEP(ax, 1) BSTEP(ay, 1)
    BSTEP(ax, 2) BSTEP(ay, 2)
    BSTEP(ax, 3) BSTEP(ay, 3)
    {   // j = lrow -> row = (j>>2)*16 + lkb*4 + (j&3); bijective over 64 rows
        int row_l = wr * 64 + ((lrow >> 2) << 4) + (lkb << 2) + (lrow & 3);
        atomicAdd(&rsum[0][row_l], ax[0]);
        atomicAdd(&rsum[1][row_l], ay[0]);
    }
    // col sums: reduce across the 4 lkb groups
#pragma unroll
    for (int nf = 0; nf < 2; ++nf) {
        float vx = csx[nf], vy = csy[nf];
        vx += __shfl_xor(vx, 16); vx += __shfl_xor(vx, 32);
        vy += __shfl_xor(vy, 16); vy += __shfl_xor(vy, 32);
        if (lkb == 0) {
            int col_l = wc * 32 + nf * 16 + lrow;
            atomicAdd(&rsum[2][col_l], vx);
            atomicAdd(&rsum[3][col_l], vy);
        }
    }
    // scalar products: wave reduce -> per-wave slot
#pragma unroll
    for (int m = 1; m < 64; m <<= 1) {
        pxy += __shfl_xor(pxy, m);
        pxx += __shfl_xor(pxx, m);
        pyy += __shfl_xor(pyy, m);
    }
    if (lane == 0) { pr[0][wid] = pxy; pr[1][wid] = pxx; pr[2][wid] = pyy; }
    __syncthreads();                 // B5

    if (tid == 0) {
        double sxy = 0, sxx = 0, syy = 0;
#pragma unroll
        for (int w = 0; w < 8; ++w) {
            sxy += (double)pr[0][w]; sxx += (double)pr[1][w]; syy += (double)pr[2][w];
        }
        double sc = diag ? 1.0 : 2.0;
        Pp[t] = sxy * sc;
        Pp[NT + t] = sxx * sc;
        Pp[2 * NT + t] = syy * sc;
    }
    if (tid < TILE) {   // each RP slot written by exactly one block
        RPx[((size_t)bi * GB + bj) * TILE + tid] = rsum[0][tid];
        RPy[((size_t)bi * GB + bj) * TILE + tid] = rsum[1][tid];
        if (!diag) {
            RPx[((size_t)bj * GB + bi) * TILE + tid] = rsum[2][tid];
            RPy[((size_t)bj * GB + bi) * TILE + tid] = rsum[3][tid];
        }
    }
}

// Fold per-tile partials into full row sums AND the 5 row-sum scalars.
__global__ __launch_bounds__(128) void row_reduce2(
    const float* __restrict__ RPx, const float* __restrict__ RPy,
    double* __restrict__ SB /* [GB][5] */)
{
    int b = blockIdx.x, t = threadIdx.x;
    double rx = 0.0, ry = 0.0;
    for (int k = 0; k < GB; ++k) {
        rx += (double)RPx[((size_t)b * GB + k) * TILE + t];
        ry += (double)RPy[((size_t)b * GB + k) * TILE + t];
    }
    double s0 = rx, s1 = ry, s2 = rx * ry, s3 = rx * rx, s4 = ry * ry;
#pragma unroll
    for (int m = 1; m < 64; m <<= 1) {
        s0 += __shfl_xor(s0, m); s1 += __shfl_xor(s1, m);
        s2 += __shfl_xor(s2, m); s3 += __shfl_xor(s3, m);
        s4 += __shfl_xor(s4, m);
    }
    __shared__ double sb[5][2];
    int lane = t & 63, w = t >> 6;
    if (lane == 0) { sb[0][w] = s0; sb[1][w] = s1; sb[2][w] = s2; sb[3][w] = s3; sb[4][w] = s4; }
    __syncthreads();
    if (t == 0)
#pragma unroll
        for (int i = 0; i < 5; ++i) SB[b * 5 + i] = sb[i][0] + sb[i][1];
}

__global__ __launch_bounds__(256) void dcor_final3(
    const double* __restrict__ SB, const double* __restrict__ Pp,
    unsigned* __restrict__ out)
{
    double sx = 0, sy = 0, sxy = 0, sxx = 0, syy = 0, pxy = 0, pxx = 0, pyy = 0;
    for (int b = threadIdx.x; b < GB; b += 256) {
        sx += SB[b * 5]; sy += SB[b * 5 + 1]; sxy += SB[b * 5 + 2];
        sxx += SB[b * 5 + 3]; syy += SB[b * 5 + 4];
    }
    for (int b = threadIdx.x; b < NT; b += 256) {
        pxy += Pp[b]; pxx += Pp[NT + b]; pyy += Pp[2 * NT + b];
    }
    __shared__ double red[8][4];
    int lane = threadIdx.x & 63, w = threadIdx.x >> 6;
#pragma unroll
    for (int m = 1; m < 64; m <<= 1) {
        sx += __shfl_xor(sx, m);  sy += __shfl_xor(sy, m);
        sxy += __shfl_xor(sxy, m); sxx += __shfl_xor(sxx, m); syy += __shfl_xor(syy, m);
        pxy += __shfl_xor(pxy, m); pxx += __shfl_xor(pxx, m); pyy += __shfl_xor(pyy, m);
    }
    if (lane == 0) {
        red[0][w] = sx;  red[1][w] = sy;  red[2][w] = sxy; red[3][w] = sxx;
        red[4][w] = syy; red[5][w] = pxy; red[6][w] = pxx; red[7][w] = pyy;
    }
    __syncthreads();
    if (threadIdx.x == 0) {
        sx  = red[0][0] + red[0][1] + red[0][2] + red[0][3];
        sy  = red[1][0] + red[1][1] + red[1][2] + red[1][3];
        sxy = red[2][0] + red[2][1] + red[2][2] + red[2][3];
        sxx = red[3][0] + red[3][1] + red[3][2] + red[3][3];
        syy = red[4][0] + red[4][1] + red[4][2] + red[4][3];
        pxy = red[5][0] + red[5][1] + red[5][2] + red[5][3];
        pxx = red[6][0] + red[6][1] + red[6][2] + red[6][3];
        pyy = red[7][0] + red[7][1] + red[7][2] + red[7][3];
        const double inv = 1.0 / (double)NR;
        double vxy = pxy - 2.0 * inv * sxy + sx * sy * inv * inv;
        double vxx = pxx - 2.0 * inv * sxx + sx * sx * inv * inv;
        double vyy = pyy - 2.0 * inv * syy + sy * sy * inv * inv;
        vxy = fmax(vxy, 0.0);
        vxx = fmax(vxx, 1e-30); vyy = fmax(vyy, 1e-30);
        double dcor = -sqrt(vxy) / sqrt(sqrt(vxx) * sqrt(vyy));
        unsigned short b = bf16_rne((float)dcor);
        out[0] = ((unsigned)b << 16) | (unsigned)b;   // f32-and-bf16 valid
    }
}

extern "C" void kernel_launch(void* const* d_in, const int* in_sizes, int n_in,
                              void* d_out, int out_size, void* d_ws, size_t ws_size,
                              hipStream_t stream)
{
    const float* x = (const float*)d_in[0];
    const float* y = (const float*)d_in[1];
    char* ws = (char*)d_ws;
    unsigned short* xb = (unsigned short*)(ws);
    unsigned short* yb = (unsigned short*)(ws + OFF_YB);
    float* nx = (float*)(ws + OFF_NX);
    float* ny = (float*)(ws + OFF_NY);
    float* RPx = (float*)(ws + OFF_RPX);
    float* RPy = (float*)(ws + OFF_RPY);
    double* Pp = (double*)(ws + OFF_PP);
    double* SB = (double*)(ws + OFF_SB);

    prep_kernel<<<4096, 256, 0, stream>>>(x, y, xb, yb, nx, ny);
    dcor_main5<<<NT, 512, 0, stream>>>(xb, yb, nx, ny, RPx, RPy, Pp);
    row_reduce2<<<GB, 128, 0, stream>>>(RPx, RPy, SB);
    dcor_final3<<<1, 256, 0, stream>>>(SB, Pp, (unsigned*)d_out);
}

// Round 8
// 97.649 us; speedup vs baseline: 1.3946x; 1.2187x over previous
//
#include <hip/hip_runtime.h>

// DcorLoss: dcor(x, y) for x,y [8192,128] fp32 -> single scalar.
//
// <HaH,HbH> = sum(a_ij b_ij) - (2/n) sum_i ra_i rb_i + Sa Sb/n^2: one fused
// pass over 128x128 pair-tiles: bf16 gram (MFMA 16x16x32) -> distances ->
// f32 block-local scalar products + row/col sums, f64 per-tile spill.
// Upper triangle only; off-diag tiles doubled + transposed col-sums.
//
// R8: epilogue VALU cuts (the profiled bottleneck, VALUBusy 51%):
//  - __builtin_amdgcn_sqrtf (raw v_sqrt_f32) instead of precise sqrtf
//    (~8 -> 1 instr; distances already carry bf16-gram noise ~2^-8)
//  - norms hoisted to registers: 18 ds_read_b32/thread instead of 128
//  - X distances kept in f32 regs (no bf16 pack/unpack round-trip)
// Structure unchanged from R7: dbuf staging via global_load_lds w=16 with
// pre-swizzled global layout, 5 barriers, butterfly row reduction, XCD
// swizzle, atomic-free RP spill + row_reduce.

typedef float f32x4 __attribute__((ext_vector_type(4)));
typedef __bf16 bf16x8 __attribute__((ext_vector_type(8)));

#define NR 8192
#define D 128
#define TILE 128
#define GB 64          /* NR / TILE */
#define NT 2080        /* GB*(GB+1)/2 */
#define BK 64

// ---------------- workspace layout (bytes) ----------------
#define OFF_YB  2097152u
#define OFF_NX  4194304u
#define OFF_NY  (OFF_NX + 32768u)
#define OFF_RPX (OFF_NY + 32768u)               /* 64*64*128 f32 = 2 MB */
#define OFF_RPY (OFF_RPX + 2097152u)            /* 2 MB */
#define OFF_PP  (OFF_RPY + 2097152u)            /* 3*2080 f64 */
#define OFF_SB  (OFF_PP + 49920u)               /* 64*5 f64 */
#define WS_NEED (OFF_SB + 2560u)

#define GLOAD_LDS16(g, l)                                                  \
    __builtin_amdgcn_global_load_lds(                                      \
        (const __attribute__((address_space(1))) unsigned*)(g),            \
        (__attribute__((address_space(3))) unsigned*)(l), 16, 0, 0)

__device__ __forceinline__ unsigned short bf16_rne(float f) {
    union { float f; unsigned u; } c; c.f = f;
    unsigned u = c.u;
    u += 0x7FFFu + ((u >> 16) & 1u);
    return (unsigned short)(u >> 16);
}

// One wave per row: fp32 -> bf16 (RNE) + fp32 row sq-norm. Output layout is
// CHUNK-SWIZZLED: within each 128B half-row, 16B chunk q stores logical
// chunk q^(row&7), so a linear global_load_lds produces the swizzled LDS
// image that the gram's XOR'd ds_read expects.
__global__ __launch_bounds__(256) void prep_kernel(
    const float* __restrict__ x, const float* __restrict__ y,
    unsigned short* __restrict__ xb, unsigned short* __restrict__ yb,
    float* __restrict__ nx, float* __restrict__ ny)
{
    int gid = blockIdx.x * 256 + threadIdx.x;
    int wave = gid >> 6;
    int lane = threadIdx.x & 63;
    const float* src; unsigned short* db; float* dn; int row;
    if (wave < NR) { src = x; db = xb; dn = nx; row = wave; }
    else           { src = y; db = yb; dn = ny; row = wave - NR; }

    const float2 v = *reinterpret_cast<const float2*>(src + (size_t)row * D + lane * 2);
    float s = v.x * v.x + v.y * v.y;
    unsigned packed = (unsigned)bf16_rne(v.x) | ((unsigned)bf16_rne(v.y) << 16);
    int h = lane >> 5, q = (lane >> 2) & 7, o = (lane & 3) * 2;
    int sidx = h * 64 + ((q ^ (row & 7)) << 3) + o;
    *reinterpret_cast<unsigned*>(db + (size_t)row * D + sidx) = packed;
#pragma unroll
    for (int m = 1; m < 64; m <<= 1) s += __shfl_xor(s, m);
    if (lane == 0) dn[row] = s;
}

// butterfly step S for a 16-value array reduced over the 16-lane lrow group
#define BSTEP(arr, S) {                                                    \
    const int b_ = (lrow >> (S)) & 1;                                      \
    _Pragma("unroll")                                                      \
    for (int i_ = 0; i_ < (8 >> (S)); ++i_) {                              \
        float k_ = b_ ? arr[2 * i_ + 1] : arr[2 * i_];                     \
        float s_ = b_ ? arr[2 * i_] : arr[2 * i_ + 1];                     \
        arr[i_] = k_ + __shfl_xor(s_, 1 << (S));                           \
    } }

// One 128x128 pair-tile per block, 8 waves (2 row x 4 col quadrants of
// 64x32), 4x2 frags of mfma_f32_16x16x32_bf16, double-buffered K-halves.
__global__ __launch_bounds__(512) void dcor_main6(
    const unsigned short* __restrict__ xb, const unsigned short* __restrict__ yb,
    const float* __restrict__ nx, const float* __restrict__ ny,
    float* __restrict__ RPx, float* __restrict__ RPy,
    double* __restrict__ Pp /* [3][NT] */)
{
    // XCD-chunked swizzle (8 XCDs, NT % 8 == 0 -> bijective)
    const int t = (blockIdx.x & 7) * (NT / 8) + (blockIdx.x >> 3);
    // triangular index t -> (bi, bj), bi <= bj
    double qd = 2.0 * GB + 1.0;
    int bi = (int)((qd - sqrt(qd * qd - 8.0 * (double)t)) * 0.5);
    while (bi > 0 && bi * GB - bi * (bi - 1) / 2 > t) --bi;
    while ((bi + 1) * GB - (bi + 1) * bi / 2 <= t) ++bi;
    const int bj = bi + (t - (bi * GB - bi * (bi - 1) / 2));
    const bool diag = (bi == bj);

    // two staging buffers: [buf][tsel][row][64 shorts] (linear, DMA dest)
    __shared__ __align__(16) unsigned short Buf[2][2][TILE][BK];
    __shared__ float nl[4][TILE];   // 0:x rows 1:x cols 2:y rows 3:y cols
    __shared__ float rsum[4][TILE]; // x-row, y-row, x-col, y-col
    __shared__ float pr[3][8];

    const int tid  = threadIdx.x;
    const int lane = tid & 63, wid = tid >> 6;
    const int wr = wid >> 2, wc = wid & 3;        // 2x4 wave grid
    const int lrow = lane & 15, lkb = lane >> 4;

    if (tid < TILE) {
        nl[0][tid] = nx[bi * TILE + tid];
        nl[1][tid] = nx[bj * TILE + tid];
        nl[2][tid] = ny[bi * TILE + tid];
        nl[3][tid] = ny[bj * TILE + tid];
        rsum[0][tid] = 0.f; rsum[1][tid] = 0.f;
        rsum[2][tid] = 0.f; rsum[3][tid] = 0.f;
    }

    // stage K-half h into buffer b: 32 x 1KB segments, pure LDS-DMA
    auto stage = [&](int b, const unsigned short* srcb, int h) {
        const char* gb = (const char*)srcb;
#pragma unroll
        for (int it = 0; it < 4; ++it) {
            int s = wid * 4 + it;
            int tsel = s >> 4;
            int r0 = (s & 15) * 8;
            unsigned short* ldsb = &Buf[b][tsel][r0][0];
            int grow = (tsel ? bj : bi) * TILE + r0 + (lane >> 3);
            const char* g = gb + (size_t)grow * 256 + h * 128 + (lane & 7) * 16;
            GLOAD_LDS16(g, ldsb);
        }
    };

    auto gram = [&](int b, f32x4 (&acc)[4][2]) {
        const char* Ti = (const char*)&Buf[b][0][0][0];
        const char* Tj = (const char*)&Buf[b][1][0][0];
#pragma unroll
        for (int kk = 0; kk < 2; ++kk) {
            const int sA = (((kk << 2) | lkb) ^ (lrow & 7)) << 4;
            bf16x8 a[4], bb[2];
#pragma unroll
            for (int m = 0; m < 4; ++m) {
                int row = wr * 64 + m * 16 + lrow;
                a[m] = *reinterpret_cast<const bf16x8*>(Ti + row * 128 + sA);
            }
#pragma unroll
            for (int nf = 0; nf < 2; ++nf) {
                int row = wc * 32 + nf * 16 + lrow;
                bb[nf] = *reinterpret_cast<const bf16x8*>(Tj + row * 128 + sA);
            }
#pragma unroll
            for (int m = 0; m < 4; ++m)
#pragma unroll
                for (int nf = 0; nf < 2; ++nf)
                    acc[m][nf] = __builtin_amdgcn_mfma_f32_16x16x32_bf16(
                        a[m], bb[nf], acc[m][nf], 0, 0, 0);
        }
    };

    // C frag: row = (lane>>4)*4 + r, col = lane&15. Norms hoisted to regs;
    // raw v_sqrt_f32 (<=1 ulp; gram itself is bf16-rounded already).
    auto to_dist = [&](f32x4 (&acc)[4][2], const float* nRw, const float* nC) {
        const float nc0 = nC[wc * 32 + lrow];
        const float nc1 = nC[wc * 32 + 16 + lrow];
#pragma unroll
        for (int m = 0; m < 4; ++m) {
            float nr[4];
#pragma unroll
            for (int r = 0; r < 4; ++r)
                nr[r] = nRw[wr * 64 + m * 16 + lkb * 4 + r];
#pragma unroll
            for (int nf = 0; nf < 2; ++nf) {
                const float nc = nf ? nc1 : nc0;
#pragma unroll
                for (int r = 0; r < 4; ++r) {
                    float sq = nr[r] + nc - 2.f * acc[m][nf][r];
                    acc[m][nf][r] = __builtin_amdgcn_sqrtf(fmaxf(sq, 0.f));
                }
            }
        }
        if (diag) {   // only 64/2080 blocks
#pragma unroll
            for (int m = 0; m < 4; ++m)
#pragma unroll
                for (int nf = 0; nf < 2; ++nf)
#pragma unroll
                    for (int r = 0; r < 4; ++r) {
                        int row_l = wr * 64 + m * 16 + lkb * 4 + r;
                        int col_l = wc * 32 + nf * 16 + lrow;
                        if (row_l == col_l) acc[m][nf][r] = 0.f;
                    }
        }
    };

    const f32x4 fz = {0.f, 0.f, 0.f, 0.f};
    f32x4 accX[4][2], accY[4][2];
#pragma unroll
    for (int m = 0; m < 4; ++m)
#pragma unroll
        for (int nf = 0; nf < 2; ++nf) { accX[m][nf] = fz; accY[m][nf] = fz; }

    // ---- double-buffered pipeline: 5 barriers ----
    stage(0, xb, 0);
    __syncthreads();                 // B1: DMA0 done (+ init visible)
    stage(1, xb, 1);                 // DMA1 flies under gram0
    gram(0, accX);
    __syncthreads();                 // B2: DMA1 done, buf0 free
    stage(0, yb, 0);                 // DMA2 flies under gram1 + to_dist
    gram(1, accX);
    to_dist(accX, nl[0], nl[1]);     // X distances stay in f32 regs
    __syncthreads();                 // B3: DMA2 done, buf1 free
    stage(1, yb, 1);                 // DMA3 flies under gram2
    gram(0, accY);
    __syncthreads();                 // B4: DMA3 done
    gram(1, accY);
    to_dist(accY, nl[2], nl[3]);

    // ---- combine ----
    float pxy = 0.f, pxx = 0.f, pyy = 0.f;
    float ax[16], ay[16];
    float csx[2] = {0.f, 0.f}, csy[2] = {0.f, 0.f};
#pragma unroll
    for (int j = 0; j < 16; ++j) { ax[j] = 0.f; ay[j] = 0.f; }

#pragma unroll
    for (int m = 0; m < 4; ++m)
#pragma unroll
        for (int nf = 0; nf < 2; ++nf)
#pragma unroll
            for (int r = 0; r < 4; ++r) {
                float dx = accX[m][nf][r], dy = accY[m][nf][r];
                pxy += dx * dy;
                pxx += dx * dx;
                pyy += dy * dy;
                ax[m * 4 + r] += dx;  ay[m * 4 + r] += dy;
                csx[nf] += dx;        csy[nf] += dy;
            }

    // butterfly: 15 shuffles reduce 16 values over the 16-lane lrow group;
    // lane ends holding the full sum for value j == lrow.
    BSTEP(ax, 0) BSTEP(ay, 0)
    BSTEP(ax, 1) BSTEP(ay, 1)
    BSTEP(ax, 2) BSTEP(ay, 2)
    BSTEP(ax, 3) BSTEP(ay, 3)
    {   // j = lrow -> row = (j>>2)*16 + lkb*4 + (j&3); bijective over 64 rows
        int row_l = wr * 64 + ((lrow >> 2) << 4) + (lkb << 2) + (lrow & 3);
        atomicAdd(&rsum[0][row_l], ax[0]);
        atomicAdd(&rsum[1][row_l], ay[0]);
    }
    // col sums: reduce across the 4 lkb groups
#pragma unroll
    for (int nf = 0; nf < 2; ++nf) {
        float vx = csx[nf], vy = csy[nf];
        vx += __shfl_xor(vx, 16); vx += __shfl_xor(vx, 32);
        vy += __shfl_xor(vy, 16); vy += __shfl_xor(vy, 32);
        if (lkb == 0) {
            int col_l = wc * 32 + nf * 16 + lrow;
            atomicAdd(&rsum[2][col_l], vx);
            atomicAdd(&rsum[3][col_l], vy);
        }
    }
    // scalar products: wave reduce -> per-wave slot
#pragma unroll
    for (int m = 1; m < 64; m <<= 1) {
        pxy += __shfl_xor(pxy, m);
        pxx += __shfl_xor(pxx, m);
        pyy += __shfl_xor(pyy, m);
    }
    if (lane == 0) { pr[0][wid] = pxy; pr[1][wid] = pxx; pr[2][wid] = pyy; }
    __syncthreads();                 // B5

    if (tid == 0) {
        double sxy = 0, sxx = 0, syy = 0;
#pragma unroll
        for (int w = 0; w < 8; ++w) {
            sxy += (double)pr[0][w]; sxx += (double)pr[1][w]; syy += (double)pr[2][w];
        }
        double sc = diag ? 1.0 : 2.0;
        Pp[t] = sxy * sc;
        Pp[NT + t] = sxx * sc;
        Pp[2 * NT + t] = syy * sc;
    }
    if (tid < TILE) {   // each RP slot written by exactly one block
        RPx[((size_t)bi * GB + bj) * TILE + tid] = rsum[0][tid];
        RPy[((size_t)bi * GB + bj) * TILE + tid] = rsum[1][tid];
        if (!diag) {
            RPx[((size_t)bj * GB + bi) * TILE + tid] = rsum[2][tid];
            RPy[((size_t)bj * GB + bi) * TILE + tid] = rsum[3][tid];
        }
    }
}

// Fold per-tile partials into full row sums AND the 5 row-sum scalars.
__global__ __launch_bounds__(128) void row_reduce2(
    const float* __restrict__ RPx, const float* __restrict__ RPy,
    double* __restrict__ SB /* [GB][5] */)
{
    int b = blockIdx.x, t = threadIdx.x;
    double rx = 0.0, ry = 0.0;
    for (int k = 0; k < GB; ++k) {
        rx += (double)RPx[((size_t)b * GB + k) * TILE + t];
        ry += (double)RPy[((size_t)b * GB + k) * TILE + t];
    }
    double s0 = rx, s1 = ry, s2 = rx * ry, s3 = rx * rx, s4 = ry * ry;
#pragma unroll
    for (int m = 1; m < 64; m <<= 1) {
        s0 += __shfl_xor(s0, m); s1 += __shfl_xor(s1, m);
        s2 += __shfl_xor(s2, m); s3 += __shfl_xor(s3, m);
        s4 += __shfl_xor(s4, m);
    }
    __shared__ double sb[5][2];
    int lane = t & 63, w = t >> 6;
    if (lane == 0) { sb[0][w] = s0; sb[1][w] = s1; sb[2][w] = s2; sb[3][w] = s3; sb[4][w] = s4; }
    __syncthreads();
    if (t == 0)
#pragma unroll
        for (int i = 0; i < 5; ++i) SB[b * 5 + i] = sb[i][0] + sb[i][1];
}

__global__ __launch_bounds__(256) void dcor_final3(
    const double* __restrict__ SB, const double* __restrict__ Pp,
    unsigned* __restrict__ out)
{
    double sx = 0, sy = 0, sxy = 0, sxx = 0, syy = 0, pxy = 0, pxx = 0, pyy = 0;
    for (int b = threadIdx.x; b < GB; b += 256) {
        sx += SB[b * 5]; sy += SB[b * 5 + 1]; sxy += SB[b * 5 + 2];
        sxx += SB[b * 5 + 3]; syy += SB[b * 5 + 4];
    }
    for (int b = threadIdx.x; b < NT; b += 256) {
        pxy += Pp[b]; pxx += Pp[NT + b]; pyy += Pp[2 * NT + b];
    }
    __shared__ double red[8][4];
    int lane = threadIdx.x & 63, w = threadIdx.x >> 6;
#pragma unroll
    for (int m = 1; m < 64; m <<= 1) {
        sx += __shfl_xor(sx, m);  sy += __shfl_xor(sy, m);
        sxy += __shfl_xor(sxy, m); sxx += __shfl_xor(sxx, m); syy += __shfl_xor(syy, m);
        pxy += __shfl_xor(pxy, m); pxx += __shfl_xor(pxx, m); pyy += __shfl_xor(pyy, m);
    }
    if (lane == 0) {
        red[0][w] = sx;  red[1][w] = sy;  red[2][w] = sxy; red[3][w] = sxx;
        red[4][w] = syy; red[5][w] = pxy; red[6][w] = pxx; red[7][w] = pyy;
    }
    __syncthreads();
    if (threadIdx.x == 0) {
        sx  = red[0][0] + red[0][1] + red[0][2] + red[0][3];
        sy  = red[1][0] + red[1][1] + red[1][2] + red[1][3];
        sxy = red[2][0] + red[2][1] + red[2][2] + red[2][3];
        sxx = red[3][0] + red[3][1] + red[3][2] + red[3][3];
        syy = red[4][0] + red[4][1] + red[4][2] + red[4][3];
        pxy = red[5][0] + red[5][1] + red[5][2] + red[5][3];
        pxx = red[6][0] + red[6][1] + red[6][2] + red[6][3];
        pyy = red[7][0] + red[7][1] + red[7][2] + red[7][3];
        const double inv = 1.0 / (double)NR;
        double vxy = pxy - 2.0 * inv * sxy + sx * sy * inv * inv;
        double vxx = pxx - 2.0 * inv * sxx + sx * sx * inv * inv;
        double vyy = pyy - 2.0 * inv * syy + sy * sy * inv * inv;
        vxy = fmax(vxy, 0.0);
        vxx = fmax(vxx, 1e-30); vyy = fmax(vyy, 1e-30);
        double dcor = -sqrt(vxy) / sqrt(sqrt(vxx) * sqrt(vyy));
        unsigned short b = bf16_rne((float)dcor);
        out[0] = ((unsigned)b << 16) | (unsigned)b;   // f32-and-bf16 valid
    }
}

extern "C" void kernel_launch(void* const* d_in, const int* in_sizes, int n_in,
                              void* d_out, int out_size, void* d_ws, size_t ws_size,
                              hipStream_t stream)
{
    const float* x = (const float*)d_in[0];
    const float* y = (const float*)d_in[1];
    char* ws = (char*)d_ws;
    unsigned short* xb = (unsigned short*)(ws);
    unsigned short* yb = (unsigned short*)(ws + OFF_YB);
    float* nx = (float*)(ws + OFF_NX);
    float* ny = (float*)(ws + OFF_NY);
    float* RPx = (float*)(ws + OFF_RPX);
    float* RPy = (float*)(ws + OFF_RPY);
    double* Pp = (double*)(ws + OFF_PP);
    double* SB = (double*)(ws + OFF_SB);

    prep_kernel<<<4096, 256, 0, stream>>>(x, y, xb, yb, nx, ny);
    dcor_main6<<<NT, 512, 0, stream>>>(xb, yb, nx, ny, RPx, RPy, Pp);
    row_reduce2<<<GB, 128, 0, stream>>>(RPx, RPy, SB);
    dcor_final3<<<1, 256, 0, stream>>>(SB, Pp, (unsigned*)d_out);
}